// Round 2
// baseline (149.438 us; speedup 1.0000x reference)
//
#include <hip/hip_runtime.h>
#include <hip/hip_bf16.h>

// HamiltonianPropagator fused kernel for MI355X (gfx950).
//
// h_t = A_t h_{t-1} + X_t, A_t = exp(i*freq*dt_t), |A|=1
//   => with P_t = exp(i*freq*cumsum(dt)_t):  h_t = P_t * S_t,
//      S_t = sum_{s<=t} conj(P_s) * X_s      (plain complex cumsum)
// X_t = (x_t @ W_in^T as complex) * dt_t;  out = [Re h; Im h] @ W_out^T + b.
//
// Round 15 = round 14 + ONE change: the per-slab trig-table reads are
// hoisted out of the serial chain into a 16 x f32x4 register prefetch
// issued at the TOP of the slab loop (before GEMM1). r14's post-mortem:
// VALU work fell 23% (trig gone, as predicted) but time rose 6% — the
// table loads were issued inside the chain region with VGPR capped at
// 128, so only ~4 could fly at once -> ~1.2K cyc exposed L2 latency per
// slab. launch_bounds(256,2) permits 256 VGPRs; spending ~64 on q[16]
// gives the loads the whole GEMM1+staging+B2 region to complete. The
// chain is now pure register math: 2 chained FMAs + 2 muls + pack.
//
//  (kept from r14)
//  (1) lgkm-only barriers: B0/B2/B3 fence LDS hand-offs without draining
//      in-flight global loads/stores (T4).
//  (2) trig table (cp, sp, cp*dt, sp*dt) per (t,c) precomputed in k_scan
//      (f64 phase reduction, identical v_sin/v_cos-on-revolutions math),
//      512 KB in workspace, L2-resident broadcast.
//
// Session law (7 failed rounds): only micro-deltas that keep the passing
// lineage's data-flow skeleton and thread roles intact are admissible.

typedef __attribute__((ext_vector_type(8))) short bf16x8;
typedef __attribute__((ext_vector_type(4))) float f32x4;

#define T_DIM 256
#define N_SEQ 1024
#define C_DIM 128
#define SLAB  16
#define NSLAB 16
#define XPST  260                         // lds_xp row stride (floats)
#define OUT0  (256u * 1024u * 128u)       // elements in output 0
#define HF_N  (N_SEQ * C_DIM)             // 131072 elements per plane

__device__ __forceinline__ short f2bf(float f) {
    union { float f; unsigned u; } v; v.f = f;
    unsigned r = (v.u + 0x7FFFu + ((v.u >> 16) & 1u)) >> 16;   // RNE
    return (short)(unsigned short)r;
}

__device__ __forceinline__ bf16x8 pack8(f32x4 a, f32x4 b) {
    bf16x8 f;
    f[0] = f2bf(a[0]); f[1] = f2bf(a[1]); f[2] = f2bf(a[2]); f[3] = f2bf(a[3]);
    f[4] = f2bf(b[0]); f[5] = f2bf(b[1]); f[6] = f2bf(b[2]); f[7] = f2bf(b[3]);
    return f;
}

// lgkm-only barrier: fences LDS producer->consumer across waves without
// draining in-flight global loads/stores (T4). Memory-clobber asm on both
// sides stops the compiler moving LDS ops across the raw s_barrier.
__device__ __forceinline__ void barrier_l() {
    asm volatile("s_waitcnt lgkmcnt(0)" ::: "memory");
    __builtin_amdgcn_s_barrier();
    asm volatile("" ::: "memory");
}

// ---- K0: inclusive cumsum of dt (double) + trig table ----
// grid 16 x 256: every block redundantly scans dt (cheap), then fills 16
// rows of tbl[t][c] = (cos, sin, cos*dt_t, sin*dt_t), phase reduced in f64.
__global__ void k_scan(const float* __restrict__ dt,
                       const float* __restrict__ log_freq,
                       f32x4* __restrict__ tbl) {
    __shared__ double s[T_DIM];
    __shared__ double frevd[C_DIM];
    int t = threadIdx.x;
    float d = dt[t];
    s[t] = (double)d;
    if (t < C_DIM)
        frevd[t] = exp((double)log_freq[t]) * 0.15915494309189535;  // freq/2pi
    __syncthreads();
    for (int off = 1; off < T_DIM; off <<= 1) {
        double add = (t >= off) ? s[t - off] : 0.0;
        __syncthreads();
        s[t] += add;
        __syncthreads();
    }
    int row  = blockIdx.x * 16 + (t >> 4);      // 16 rows per block
    int cgrp = t & 15;                          // 8 channels per thread
    double D  = s[row];
    float dtf = dt[row];
#pragma unroll
    for (int j = 0; j < 8; ++j) {
        int c = cgrp * 8 + j;
        double rev = frevd[c] * D;              // revolutions, f64 reduction
        rev -= floor(rev);
        float rf = (float)rev;
        float sp, cp;
        asm("v_sin_f32 %0, %1" : "=v"(sp) : "v"(rf));
        asm("v_cos_f32 %0, %1" : "=v"(cp) : "v"(rf));
        f32x4 e;
        e[0] = cp; e[1] = sp; e[2] = cp * dtf; e[3] = sp * dtf;
        tbl[(size_t)row * C_DIM + c] = e;
    }
}

// ---- K1: fused propagate, one block per spatial site ----
__global__ __launch_bounds__(256, 2) void k_main(
    const float* __restrict__ x, const float* __restrict__ W_in,
    const float* __restrict__ W_out, const float* __restrict__ b_out,
    const f32x4* __restrict__ tbl,
    float* __restrict__ out, int write_imag)
{
    __shared__ __align__(16) short lds_x[2][SLAB * C_DIM];    // 2 x 16x128 bf16, swizzled
    __shared__ __align__(16) float lds_xp[SLAB * XPST];       // 16x260 f32
    __shared__ __align__(16) short lds_h[SLAB * 2 * C_DIM];   // 16x256 bf16, swizzled

    const int n    = blockIdx.x;
    const int tid  = threadIdx.x;
    const int lane = tid & 63;
    const int wv   = tid >> 6;       // wave 0..3
    const int lrow = lane & 15;
    const int lgrp = lane >> 4;

    // --- Weight-stationary fragments (identical to round 6/10) ---
    bf16x8 B1[4][4];
#pragma unroll
    for (int s = 0; s < 4; ++s)
#pragma unroll
        for (int t = 0; t < 4; ++t) {
            int col = wv * 64 + t * 16 + lrow;
            int k0  = s * 32 + lgrp * 8;
            const float* p = W_in + (size_t)col * C_DIM + k0;
            B1[s][t] = pack8(*(const f32x4*)p, *(const f32x4*)(p + 4));
        }
    bf16x8 B2[8][2];
#pragma unroll
    for (int s = 0; s < 8; ++s)
#pragma unroll
        for (int t = 0; t < 2; ++t) {
            int col = wv * 32 + t * 16 + lrow;
            int k0  = s * 32 + lgrp * 8;
            const float* p = W_out + (size_t)col * (2 * C_DIM) + k0;
            B2[s][t] = pack8(*(const f32x4*)p, *(const f32x4*)(p + 4));
        }
    float bo0 = b_out[wv * 32 + lrow];
    float bo1 = b_out[wv * 32 + 16 + lrow];

    float Sr = 0.f, Si = 0.f;        // running complex sum (threads tid<128, c=tid)
    const int trow = tid >> 4, cg = tid & 15;
    const int sbyte = trow * 256 + ((cg * 16) ^ ((trow & 7) << 4));

    // --- prologue: stage slab 0 into buf 0; issue slab 1's loads ---
    f32x4 pf0, pf1;
    {
        const float* p = x + ((size_t)trow * N_SEQ + n) * C_DIM + cg * 8;
        pf0 = *(const f32x4*)p;
        pf1 = *(const f32x4*)(p + 4);
    }
    *(bf16x8*)((char*)lds_x[0] + sbyte) = pack8(pf0, pf1);
    {
        const float* p = x + ((size_t)(SLAB + trow) * N_SEQ + n) * C_DIM + cg * 8;
        pf0 = *(const f32x4*)p;
        pf1 = *(const f32x4*)(p + 4);
    }
    barrier_l();                                           // B0 (prologue only)

    for (int slab = 0; slab < NSLAB; ++slab) {
        const int t0 = slab * SLAB;

        // --- table prefetch: issue ALL 16 q-loads now; they complete under
        //     GEMM1 + staging + B2. First use (the chain) is after B2, so
        //     the s_waitcnt lands there and the latency is fully hidden.
        //     ~64 extra VGPRs; launch_bounds(256,2) caps at 256 so occupancy
        //     is unchanged. ---
        f32x4 q[SLAB];
        if (tid < C_DIM) {
            const f32x4* tb = tbl + (size_t)t0 * C_DIM + tid;
#pragma unroll
            for (int tt = 0; tt < SLAB; ++tt)
                q[tt] = tb[(size_t)tt * C_DIM];
        }

        // --- GEMM1: x_proj = x_slab @ W_in^T  (16 x 256), from buf slab&1 ---
        f32x4 acc1[4];
#pragma unroll
        for (int t = 0; t < 4; ++t) acc1[t] = (f32x4){0.f, 0.f, 0.f, 0.f};
#pragma unroll
        for (int s = 0; s < 4; ++s) {
            int ab = lrow * 256 + ((s * 64 + lgrp * 16) ^ ((lrow & 7) << 4));
            bf16x8 af = *(const bf16x8*)((const char*)lds_x[slab & 1] + ab);
#pragma unroll
            for (int t = 0; t < 4; ++t)
                acc1[t] = __builtin_amdgcn_mfma_f32_16x16x32_bf16(af, B1[s][t], acc1[t], 0, 0, 0);
        }

        // --- stage next slab into the other buffer; issue slab+2's loads ---
        // (write targets buf[(slab+1)&1], read only after B2+B3 of this slab;
        //  its previous reader was GEMM1(slab-1), fenced by B2/B3(slab-1).)
        if (slab < NSLAB - 1)
            *(bf16x8*)((char*)lds_x[(slab + 1) & 1] + sbyte) = pack8(pf0, pf1);
        if (slab < NSLAB - 2) {
            const float* p = x + ((size_t)(t0 + 2 * SLAB + trow) * N_SEQ + n) * C_DIM + cg * 8;
            pf0 = *(const f32x4*)p;
            pf1 = *(const f32x4*)(p + 4);
        }

#pragma unroll
        for (int t = 0; t < 4; ++t)
#pragma unroll
            for (int r = 0; r < 4; ++r)
                lds_xp[(lgrp * 4 + r) * XPST + wv * 64 + t * 16 + lrow] = acc1[t][r];
        barrier_l();                                       // B2 (lgkm only: the
        // slab+2 global prefetch and the q-loads stay in flight across it)

        // --- pointwise: Y = conj(P)*X*dt ; S += Y ; h = P*S  (pure VALU) ---
        if (tid < C_DIM) {
            __builtin_amdgcn_s_setprio(1);                 // favor the serial chain
#pragma unroll
            for (int tt = 0; tt < SLAB; ++tt) {
                float xr = lds_xp[tt * XPST + tid];
                float xi = lds_xp[tt * XPST + C_DIM + tid];
                Sr = fmaf(q[tt][2], xr, fmaf(q[tt][3], xi, Sr));   // the only serial deps
                Si = fmaf(q[tt][2], xi, fmaf(-q[tt][3], xr, Si));
                float hr = q[tt][0] * Sr - q[tt][1] * Si;
                float hi = q[tt][1] * Sr + q[tt][0] * Si;
                int swz = (tt & 7) << 4;
                *(short*)((char*)lds_h + tt * 512 + ((tid * 2) ^ swz))             = f2bf(hr);
                *(short*)((char*)lds_h + tt * 512 + (((C_DIM + tid) * 2) ^ swz))   = f2bf(hi);
                if (t0 + tt == T_DIM - 1) {
                    out[OUT0 + (size_t)n * C_DIM + tid] = hr;       // real plane
                    if (write_imag)
                        out[OUT0 + HF_N + (size_t)n * C_DIM + tid] = hi;
                }
            }
            __builtin_amdgcn_s_setprio(0);
        }
        barrier_l();                                       // B3 (lgkm only)

        // --- GEMM2: out_slab = h_cat @ W_out^T  (16 x 128) ---
        f32x4 acc2[2];
        acc2[0] = (f32x4){0.f, 0.f, 0.f, 0.f};
        acc2[1] = (f32x4){0.f, 0.f, 0.f, 0.f};
#pragma unroll
        for (int s = 0; s < 8; ++s) {
            int ab = lrow * 512 + ((s * 64 + lgrp * 16) ^ ((lrow & 7) << 4));
            bf16x8 af = *(const bf16x8*)((const char*)lds_h + ab);
#pragma unroll
            for (int t = 0; t < 2; ++t)
                acc2[t] = __builtin_amdgcn_mfma_f32_16x16x32_bf16(af, B2[s][t], acc2[t], 0, 0, 0);
        }
#pragma unroll
        for (int r = 0; r < 4; ++r) {
            size_t row = (size_t)(t0 + lgrp * 4 + r);
            out[(row * N_SEQ + n) * C_DIM + wv * 32 + lrow]      = acc2[0][r] + bo0;
            out[(row * N_SEQ + n) * C_DIM + wv * 32 + 16 + lrow] = acc2[1][r] + bo1;
        }
        // no trailing barrier (r10 proof unchanged): GEMM2's lds_h reads vs
        // next pointwise writes fenced by B2(next); lds_x buffer alternation
        // fenced by B2/B3. Each wave's own ds_reads are drained by its
        // lgkmcnt(0) at the next barrier before any producer can overwrite.
    }
}

extern "C" void kernel_launch(void* const* d_in, const int* in_sizes, int n_in,
                              void* d_out, int out_size, void* d_ws, size_t ws_size,
                              hipStream_t stream) {
    const float* x        = (const float*)d_in[0];
    const float* dt       = (const float*)d_in[1];
    const float* log_freq = (const float*)d_in[2];
    const float* W_in     = (const float*)d_in[3];
    const float* W_out    = (const float*)d_in[4];
    const float* b_out    = (const float*)d_in[5];
    float* out = (float*)d_out;

    f32x4* tbl = (f32x4*)d_ws;                        // 256*128*16 B = 512 KB

    int write_imag = (out_size >= (int)(OUT0 + 2u * HF_N)) ? 1 : 0;

    k_scan<<<16, T_DIM, 0, stream>>>(dt, log_freq, tbl);
    k_main<<<N_SEQ, 256, 0, stream>>>(x, W_in, W_out, b_out, tbl, out, write_imag);
}

// Round 5
// 131.461 us; speedup vs baseline: 1.1367x; 1.1367x over previous
//
#include <hip/hip_runtime.h>
#include <hip/hip_bf16.h>

// HamiltonianPropagator fused kernel for MI355X (gfx950).
//
// h_t = A_t h_{t-1} + X_t, A_t = exp(i*freq*dt_t), |A|=1
//   => with P_t = exp(i*freq*cumsum(dt)_t):  h_t = P_t * S_t,
//      S_t = sum_{s<=t} conj(P_s) * X_s      (plain complex cumsum)
// X_t = (x_t @ W_in^T as complex) * dt_t;  out = [Re h; Im h] @ W_out^T + b.
//
// Round 18 = BYTE-EXACT revert to the round-0 kernel (r13 lineage,
// passed at 131.0 / 133.4 us).
//
// Session post-mortem to date:
//  - r14 (lgkm-only barriers + trig table): PASS but 140.7 us. Trig is NOT
//    on the critical path (the Sr/Si FMA chain is); table loads added L2
//    latency into the serial region.
//  - r15 (register-prefetch the table): compiler sank the prefetch
//    (VGPR stayed 128); 149 us. Voided.
//  - r16/r17 (__launch_bounds__(256,4), with asm trig and builtin trig):
//    BOTH fail with identical absmax 488 on h_final while out stays
//    near-threshold -> h_final plane effectively lost at 4 blocks/CU.
//    Mechanism unidentified; two different schedules, same failure =>
//    occupancy-raising via launch bounds is INADMISSIBLE for this
//    structure. Abandoned.
//
// Session law (11 failed rounds across sessions): only micro-deltas that
// keep the passing lineage's data-flow skeleton, thread roles, launch
// bounds, and chain schedule intact are admissible.

typedef __attribute__((ext_vector_type(8))) short bf16x8;
typedef __attribute__((ext_vector_type(4))) float f32x4;
typedef __attribute__((ext_vector_type(2))) float f32x2;

#define T_DIM 256
#define N_SEQ 1024
#define C_DIM 128
#define SLAB  16
#define NSLAB 16
#define XPST  260                         // lds_xp row stride (floats)
#define OUT0  (256u * 1024u * 128u)       // elements in output 0
#define HF_N  (N_SEQ * C_DIM)             // 131072 elements per plane

__device__ __forceinline__ short f2bf(float f) {
    union { float f; unsigned u; } v; v.f = f;
    unsigned r = (v.u + 0x7FFFu + ((v.u >> 16) & 1u)) >> 16;   // RNE
    return (short)(unsigned short)r;
}

__device__ __forceinline__ bf16x8 pack8(f32x4 a, f32x4 b) {
    bf16x8 f;
    f[0] = f2bf(a[0]); f[1] = f2bf(a[1]); f[2] = f2bf(a[2]); f[3] = f2bf(a[3]);
    f[4] = f2bf(b[0]); f[5] = f2bf(b[1]); f[6] = f2bf(b[2]); f[7] = f2bf(b[3]);
    return f;
}

// ---- K0: inclusive cumsum of dt in double; emit (D_t, dt_t) f32 pairs ----
__global__ void k_scan(const float* __restrict__ dt, float* __restrict__ Ddt) {
    __shared__ double s[T_DIM];
    int t = threadIdx.x;
    float d = dt[t];
    s[t] = (double)d;
    __syncthreads();
    for (int off = 1; off < T_DIM; off <<= 1) {
        double add = (t >= off) ? s[t - off] : 0.0;
        __syncthreads();
        s[t] += add;
        __syncthreads();
    }
    Ddt[2 * t]     = (float)s[t];
    Ddt[2 * t + 1] = d;
}

// ---- K1: fused propagate, one block per spatial site ----
__global__ __launch_bounds__(256, 2) void k_main(
    const float* __restrict__ x, const float* __restrict__ W_in,
    const float* __restrict__ W_out, const float* __restrict__ b_out,
    const float* __restrict__ log_freq, const float* __restrict__ Ddt,
    float* __restrict__ out, int write_imag)
{
    __shared__ __align__(16) short lds_x[2][SLAB * C_DIM];    // 2 x 16x128 bf16, swizzled
    __shared__ __align__(16) float lds_xp[SLAB * XPST];       // 16x260 f32
    __shared__ __align__(16) short lds_h[SLAB * 2 * C_DIM];   // 16x256 bf16, swizzled
    __shared__ __align__(8)  f32x2 lds_ddt[T_DIM];            // (D_t, dt_t)

    const int n    = blockIdx.x;
    const int tid  = threadIdx.x;
    const int lane = tid & 63;
    const int wv   = tid >> 6;       // wave 0..3
    const int lrow = lane & 15;
    const int lgrp = lane >> 4;

    // stage (D,dt) pairs once (first read is after B0)
    lds_ddt[tid] = *(const f32x2*)(Ddt + 2 * tid);

    // per-thread frequency in revolutions (f64 exp, once)
    const float frev = (float)(exp((double)log_freq[tid & 127]) * 0.15915494309189535);

    // --- Weight-stationary fragments (identical to round 6/10) ---
    bf16x8 B1[4][4];
#pragma unroll
    for (int s = 0; s < 4; ++s)
#pragma unroll
        for (int t = 0; t < 4; ++t) {
            int col = wv * 64 + t * 16 + lrow;
            int k0  = s * 32 + lgrp * 8;
            const float* p = W_in + (size_t)col * C_DIM + k0;
            B1[s][t] = pack8(*(const f32x4*)p, *(const f32x4*)(p + 4));
        }
    bf16x8 B2[8][2];
#pragma unroll
    for (int s = 0; s < 8; ++s)
#pragma unroll
        for (int t = 0; t < 2; ++t) {
            int col = wv * 32 + t * 16 + lrow;
            int k0  = s * 32 + lgrp * 8;
            const float* p = W_out + (size_t)col * (2 * C_DIM) + k0;
            B2[s][t] = pack8(*(const f32x4*)p, *(const f32x4*)(p + 4));
        }
    float bo0 = b_out[wv * 32 + lrow];
    float bo1 = b_out[wv * 32 + 16 + lrow];

    float Sr = 0.f, Si = 0.f;        // running complex sum (threads tid<128, c=tid)
    const int trow = tid >> 4, cg = tid & 15;
    const int sbyte = trow * 256 + ((cg * 16) ^ ((trow & 7) << 4));

    // --- prologue: stage slab 0 into buf 0; issue slab 1's loads ---
    f32x4 pf0, pf1;
    {
        const float* p = x + ((size_t)trow * N_SEQ + n) * C_DIM + cg * 8;
        pf0 = *(const f32x4*)p;
        pf1 = *(const f32x4*)(p + 4);
    }
    *(bf16x8*)((char*)lds_x[0] + sbyte) = pack8(pf0, pf1);
    {
        const float* p = x + ((size_t)(SLAB + trow) * N_SEQ + n) * C_DIM + cg * 8;
        pf0 = *(const f32x4*)p;
        pf1 = *(const f32x4*)(p + 4);
    }
    __syncthreads();                                       // B0 (prologue only)

    for (int slab = 0; slab < NSLAB; ++slab) {
        const int t0 = slab * SLAB;

        // --- GEMM1: x_proj = x_slab @ W_in^T  (16 x 256), from buf slab&1 ---
        f32x4 acc1[4];
#pragma unroll
        for (int t = 0; t < 4; ++t) acc1[t] = (f32x4){0.f, 0.f, 0.f, 0.f};
#pragma unroll
        for (int s = 0; s < 4; ++s) {
            int ab = lrow * 256 + ((s * 64 + lgrp * 16) ^ ((lrow & 7) << 4));
            bf16x8 af = *(const bf16x8*)((const char*)lds_x[slab & 1] + ab);
#pragma unroll
            for (int t = 0; t < 4; ++t)
                acc1[t] = __builtin_amdgcn_mfma_f32_16x16x32_bf16(af, B1[s][t], acc1[t], 0, 0, 0);
        }

        // --- stage next slab into the other buffer; issue slab+2's loads ---
        // (write targets buf[(slab+1)&1], read only after B2+B3 of this slab;
        //  its previous reader was GEMM1(slab-1), fenced by B2/B3(slab-1).)
        if (slab < NSLAB - 1)
            *(bf16x8*)((char*)lds_x[(slab + 1) & 1] + sbyte) = pack8(pf0, pf1);
        if (slab < NSLAB - 2) {
            const float* p = x + ((size_t)(t0 + 2 * SLAB + trow) * N_SEQ + n) * C_DIM + cg * 8;
            pf0 = *(const f32x4*)p;
            pf1 = *(const f32x4*)(p + 4);
        }

#pragma unroll
        for (int t = 0; t < 4; ++t)
#pragma unroll
            for (int r = 0; r < 4; ++r)
                lds_xp[(lgrp * 4 + r) * XPST + wv * 64 + t * 16 + lrow] = acc1[t][r];
        __syncthreads();                                   // B2

        // --- pointwise: on-the-fly P; Y = conj(P)*X*dt ; S += Y ; h = P*S ---
        if (tid < C_DIM) {
            __builtin_amdgcn_s_setprio(1);                 // favor the serial chain
#pragma unroll
            for (int tt = 0; tt < SLAB; ++tt) {
                f32x2 dd = lds_ddt[t0 + tt];               // (D_t, dt_t) broadcast
                float rev = frev * dd[0];
                rev -= floorf(rev);
                float sp, cp;
                asm("v_sin_f32 %0, %1" : "=v"(sp) : "v"(rev));
                asm("v_cos_f32 %0, %1" : "=v"(cp) : "v"(rev));
                float q2 = cp * dd[1], q3 = sp * dd[1];
                float xr = lds_xp[tt * XPST + tid];
                float xi = lds_xp[tt * XPST + C_DIM + tid];
                Sr += q2 * xr + q3 * xi;
                Si += q2 * xi - q3 * xr;
                float hr = cp * Sr - sp * Si;
                float hi = sp * Sr + cp * Si;
                int swz = (tt & 7) << 4;
                *(short*)((char*)lds_h + tt * 512 + ((tid * 2) ^ swz))             = f2bf(hr);
                *(short*)((char*)lds_h + tt * 512 + (((C_DIM + tid) * 2) ^ swz))   = f2bf(hi);
                if (t0 + tt == T_DIM - 1) {
                    out[OUT0 + (size_t)n * C_DIM + tid] = hr;       // real plane
                    if (write_imag)
                        out[OUT0 + HF_N + (size_t)n * C_DIM + tid] = hi;
                }
            }
            __builtin_amdgcn_s_setprio(0);
        }
        __syncthreads();                                   // B3

        // --- GEMM2: out_slab = h_cat @ W_out^T  (16 x 128) ---
        f32x4 acc2[2];
        acc2[0] = (f32x4){0.f, 0.f, 0.f, 0.f};
        acc2[1] = (f32x4){0.f, 0.f, 0.f, 0.f};
#pragma unroll
        for (int s = 0; s < 8; ++s) {
            int ab = lrow * 512 + ((s * 64 + lgrp * 16) ^ ((lrow & 7) << 4));
            bf16x8 af = *(const bf16x8*)((const char*)lds_h + ab);
#pragma unroll
            for (int t = 0; t < 2; ++t)
                acc2[t] = __builtin_amdgcn_mfma_f32_16x16x32_bf16(af, B2[s][t], acc2[t], 0, 0, 0);
        }
#pragma unroll
        for (int r = 0; r < 4; ++r) {
            size_t row = (size_t)(t0 + lgrp * 4 + r);
            out[(row * N_SEQ + n) * C_DIM + wv * 32 + lrow]      = acc2[0][r] + bo0;
            out[(row * N_SEQ + n) * C_DIM + wv * 32 + 16 + lrow] = acc2[1][r] + bo1;
        }
        // no trailing barrier (r10 proof unchanged): GEMM2's lds_h reads vs
        // next pointwise writes fenced by B2(next); lds_x buffer alternation
        // fenced by B2/B3.
    }
}

extern "C" void kernel_launch(void* const* d_in, const int* in_sizes, int n_in,
                              void* d_out, int out_size, void* d_ws, size_t ws_size,
                              hipStream_t stream) {
    const float* x        = (const float*)d_in[0];
    const float* dt       = (const float*)d_in[1];
    const float* log_freq = (const float*)d_in[2];
    const float* W_in     = (const float*)d_in[3];
    const float* W_out    = (const float*)d_in[4];
    const float* b_out    = (const float*)d_in[5];
    float* out = (float*)d_out;

    float* Ddt = (float*)d_ws;                        // 512 f32 = 2 KB

    int write_imag = (out_size >= (int)(OUT0 + 2u * HF_N)) ? 1 : 0;

    k_scan<<<1, T_DIM, 0, stream>>>(dt, Ddt);
    k_main<<<N_SEQ, 256, 0, stream>>>(x, W_in, W_out, b_out, log_freq, Ddt, out, write_imag);
}

// Round 6
// 131.423 us; speedup vs baseline: 1.1371x; 1.0003x over previous
//
#include <hip/hip_runtime.h>
#include <hip/hip_bf16.h>

// HamiltonianPropagator fused kernel for MI355X (gfx950).
//
// h_t = A_t h_{t-1} + X_t, A_t = exp(i*freq*dt_t), |A|=1
//   => with P_t = exp(i*freq*cumsum(dt)_t):  h_t = P_t * S_t,
//      S_t = sum_{s<=t} conj(P_s) * X_s      (plain complex cumsum)
// X_t = (x_t @ W_in^T as complex) * dt_t;  out = [Re h; Im h] @ W_out^T + b.
//
// Round 19 = round 18 (byte-exact passing baseline, 131.5 us) + EXACTLY ONE
// change: __syncthreads -> lgkm-only barrier (s_waitcnt lgkmcnt(0) +
// s_barrier) at B0/B2/B3 in k_main. Isolating the HALF of r14 that was
// never tested alone (r14 bundled it with the trig table, which caused the
// regression; r14 PASSED correctness, so this barrier form is proven safe
// on this exact skeleton — unlike launch-bounds, which corrupts).
//
// Why it should win: __syncthreads drains vmcnt(0)+expcnt(0) per wave at
// every barrier. At B2 each wave drains its 2 just-issued prefetch loads
// (full L3/HBM latency exposed) + 8 HBM store acks from the previous
// slab's GEMM2. ~1-2K stall cyc x 16 slabs x 2 rounds ~ 13-25 us that
// correctness never needed: cross-wave hand-offs are all LDS (lgkm);
// prefetch results are register-dep-waited; global stores are disjoint.
//
// Pre-committed: unchanged dur => drains aren't the cost, declare ceiling
// next round. Regression >5us => revert, declare ceiling.
//
// Session law: only micro-deltas keeping the passing lineage's data-flow
// skeleton, thread roles, launch bounds, and chain schedule intact.
// launch_bounds(256,4): INADMISSIBLE (r16/r17 corrupt h_final).

typedef __attribute__((ext_vector_type(8))) short bf16x8;
typedef __attribute__((ext_vector_type(4))) float f32x4;
typedef __attribute__((ext_vector_type(2))) float f32x2;

#define T_DIM 256
#define N_SEQ 1024
#define C_DIM 128
#define SLAB  16
#define NSLAB 16
#define XPST  260                         // lds_xp row stride (floats)
#define OUT0  (256u * 1024u * 128u)       // elements in output 0
#define HF_N  (N_SEQ * C_DIM)             // 131072 elements per plane

__device__ __forceinline__ short f2bf(float f) {
    union { float f; unsigned u; } v; v.f = f;
    unsigned r = (v.u + 0x7FFFu + ((v.u >> 16) & 1u)) >> 16;   // RNE
    return (short)(unsigned short)r;
}

__device__ __forceinline__ bf16x8 pack8(f32x4 a, f32x4 b) {
    bf16x8 f;
    f[0] = f2bf(a[0]); f[1] = f2bf(a[1]); f[2] = f2bf(a[2]); f[3] = f2bf(a[3]);
    f[4] = f2bf(b[0]); f[5] = f2bf(b[1]); f[6] = f2bf(b[2]); f[7] = f2bf(b[3]);
    return f;
}

// lgkm-only barrier: fences LDS producer->consumer across waves without
// draining in-flight global loads/store-acks (T4). Memory-clobber asm on
// both sides stops the compiler moving LDS ops across the raw s_barrier.
// Proven correctness-safe on this skeleton by r14 (passed, absmax 0.25).
__device__ __forceinline__ void barrier_l() {
    asm volatile("s_waitcnt lgkmcnt(0)" ::: "memory");
    __builtin_amdgcn_s_barrier();
    asm volatile("" ::: "memory");
}

// ---- K0: inclusive cumsum of dt in double; emit (D_t, dt_t) f32 pairs ----
__global__ void k_scan(const float* __restrict__ dt, float* __restrict__ Ddt) {
    __shared__ double s[T_DIM];
    int t = threadIdx.x;
    float d = dt[t];
    s[t] = (double)d;
    __syncthreads();
    for (int off = 1; off < T_DIM; off <<= 1) {
        double add = (t >= off) ? s[t - off] : 0.0;
        __syncthreads();
        s[t] += add;
        __syncthreads();
    }
    Ddt[2 * t]     = (float)s[t];
    Ddt[2 * t + 1] = d;
}

// ---- K1: fused propagate, one block per spatial site ----
__global__ __launch_bounds__(256, 2) void k_main(
    const float* __restrict__ x, const float* __restrict__ W_in,
    const float* __restrict__ W_out, const float* __restrict__ b_out,
    const float* __restrict__ log_freq, const float* __restrict__ Ddt,
    float* __restrict__ out, int write_imag)
{
    __shared__ __align__(16) short lds_x[2][SLAB * C_DIM];    // 2 x 16x128 bf16, swizzled
    __shared__ __align__(16) float lds_xp[SLAB * XPST];       // 16x260 f32
    __shared__ __align__(16) short lds_h[SLAB * 2 * C_DIM];   // 16x256 bf16, swizzled
    __shared__ __align__(8)  f32x2 lds_ddt[T_DIM];            // (D_t, dt_t)

    const int n    = blockIdx.x;
    const int tid  = threadIdx.x;
    const int lane = tid & 63;
    const int wv   = tid >> 6;       // wave 0..3
    const int lrow = lane & 15;
    const int lgrp = lane >> 4;

    // stage (D,dt) pairs once (first read is after B0)
    lds_ddt[tid] = *(const f32x2*)(Ddt + 2 * tid);

    // per-thread frequency in revolutions (f64 exp, once)
    const float frev = (float)(exp((double)log_freq[tid & 127]) * 0.15915494309189535);

    // --- Weight-stationary fragments (identical to round 6/10) ---
    bf16x8 B1[4][4];
#pragma unroll
    for (int s = 0; s < 4; ++s)
#pragma unroll
        for (int t = 0; t < 4; ++t) {
            int col = wv * 64 + t * 16 + lrow;
            int k0  = s * 32 + lgrp * 8;
            const float* p = W_in + (size_t)col * C_DIM + k0;
            B1[s][t] = pack8(*(const f32x4*)p, *(const f32x4*)(p + 4));
        }
    bf16x8 B2[8][2];
#pragma unroll
    for (int s = 0; s < 8; ++s)
#pragma unroll
        for (int t = 0; t < 2; ++t) {
            int col = wv * 32 + t * 16 + lrow;
            int k0  = s * 32 + lgrp * 8;
            const float* p = W_out + (size_t)col * (2 * C_DIM) + k0;
            B2[s][t] = pack8(*(const f32x4*)p, *(const f32x4*)(p + 4));
        }
    float bo0 = b_out[wv * 32 + lrow];
    float bo1 = b_out[wv * 32 + 16 + lrow];

    float Sr = 0.f, Si = 0.f;        // running complex sum (threads tid<128, c=tid)
    const int trow = tid >> 4, cg = tid & 15;
    const int sbyte = trow * 256 + ((cg * 16) ^ ((trow & 7) << 4));

    // --- prologue: stage slab 0 into buf 0; issue slab 1's loads ---
    f32x4 pf0, pf1;
    {
        const float* p = x + ((size_t)trow * N_SEQ + n) * C_DIM + cg * 8;
        pf0 = *(const f32x4*)p;
        pf1 = *(const f32x4*)(p + 4);
    }
    *(bf16x8*)((char*)lds_x[0] + sbyte) = pack8(pf0, pf1);
    {
        const float* p = x + ((size_t)(SLAB + trow) * N_SEQ + n) * C_DIM + cg * 8;
        pf0 = *(const f32x4*)p;
        pf1 = *(const f32x4*)(p + 4);
    }
    barrier_l();                                           // B0 (prologue only)

    for (int slab = 0; slab < NSLAB; ++slab) {
        const int t0 = slab * SLAB;

        // --- GEMM1: x_proj = x_slab @ W_in^T  (16 x 256), from buf slab&1 ---
        f32x4 acc1[4];
#pragma unroll
        for (int t = 0; t < 4; ++t) acc1[t] = (f32x4){0.f, 0.f, 0.f, 0.f};
#pragma unroll
        for (int s = 0; s < 4; ++s) {
            int ab = lrow * 256 + ((s * 64 + lgrp * 16) ^ ((lrow & 7) << 4));
            bf16x8 af = *(const bf16x8*)((const char*)lds_x[slab & 1] + ab);
#pragma unroll
            for (int t = 0; t < 4; ++t)
                acc1[t] = __builtin_amdgcn_mfma_f32_16x16x32_bf16(af, B1[s][t], acc1[t], 0, 0, 0);
        }

        // --- stage next slab into the other buffer; issue slab+2's loads ---
        // (write targets buf[(slab+1)&1], read only after B2+B3 of this slab;
        //  its previous reader was GEMM1(slab-1), fenced by B2/B3(slab-1).)
        if (slab < NSLAB - 1)
            *(bf16x8*)((char*)lds_x[(slab + 1) & 1] + sbyte) = pack8(pf0, pf1);
        if (slab < NSLAB - 2) {
            const float* p = x + ((size_t)(t0 + 2 * SLAB + trow) * N_SEQ + n) * C_DIM + cg * 8;
            pf0 = *(const f32x4*)p;
            pf1 = *(const f32x4*)(p + 4);
        }

#pragma unroll
        for (int t = 0; t < 4; ++t)
#pragma unroll
            for (int r = 0; r < 4; ++r)
                lds_xp[(lgrp * 4 + r) * XPST + wv * 64 + t * 16 + lrow] = acc1[t][r];
        barrier_l();                                       // B2 (lgkm only: the
        // slab+2 prefetch loads and prev-slab store acks stay in flight)

        // --- pointwise: on-the-fly P; Y = conj(P)*X*dt ; S += Y ; h = P*S ---
        if (tid < C_DIM) {
            __builtin_amdgcn_s_setprio(1);                 // favor the serial chain
#pragma unroll
            for (int tt = 0; tt < SLAB; ++tt) {
                f32x2 dd = lds_ddt[t0 + tt];               // (D_t, dt_t) broadcast
                float rev = frev * dd[0];
                rev -= floorf(rev);
                float sp, cp;
                asm("v_sin_f32 %0, %1" : "=v"(sp) : "v"(rev));
                asm("v_cos_f32 %0, %1" : "=v"(cp) : "v"(rev));
                float q2 = cp * dd[1], q3 = sp * dd[1];
                float xr = lds_xp[tt * XPST + tid];
                float xi = lds_xp[tt * XPST + C_DIM + tid];
                Sr += q2 * xr + q3 * xi;
                Si += q2 * xi - q3 * xr;
                float hr = cp * Sr - sp * Si;
                float hi = sp * Sr + cp * Si;
                int swz = (tt & 7) << 4;
                *(short*)((char*)lds_h + tt * 512 + ((tid * 2) ^ swz))             = f2bf(hr);
                *(short*)((char*)lds_h + tt * 512 + (((C_DIM + tid) * 2) ^ swz))   = f2bf(hi);
                if (t0 + tt == T_DIM - 1) {
                    out[OUT0 + (size_t)n * C_DIM + tid] = hr;       // real plane
                    if (write_imag)
                        out[OUT0 + HF_N + (size_t)n * C_DIM + tid] = hi;
                }
            }
            __builtin_amdgcn_s_setprio(0);
        }
        barrier_l();                                       // B3 (lgkm only)

        // --- GEMM2: out_slab = h_cat @ W_out^T  (16 x 128) ---
        f32x4 acc2[2];
        acc2[0] = (f32x4){0.f, 0.f, 0.f, 0.f};
        acc2[1] = (f32x4){0.f, 0.f, 0.f, 0.f};
#pragma unroll
        for (int s = 0; s < 8; ++s) {
            int ab = lrow * 512 + ((s * 64 + lgrp * 16) ^ ((lrow & 7) << 4));
            bf16x8 af = *(const bf16x8*)((const char*)lds_h + ab);
#pragma unroll
            for (int t = 0; t < 2; ++t)
                acc2[t] = __builtin_amdgcn_mfma_f32_16x16x32_bf16(af, B2[s][t], acc2[t], 0, 0, 0);
        }
#pragma unroll
        for (int r = 0; r < 4; ++r) {
            size_t row = (size_t)(t0 + lgrp * 4 + r);
            out[(row * N_SEQ + n) * C_DIM + wv * 32 + lrow]      = acc2[0][r] + bo0;
            out[(row * N_SEQ + n) * C_DIM + wv * 32 + 16 + lrow] = acc2[1][r] + bo1;
        }
        // no trailing barrier (r10 proof unchanged): GEMM2's lds_h reads vs
        // next pointwise writes fenced by B2(next); lds_x buffer alternation
        // fenced by B2/B3. Each wave's own ds_reads are drained by its
        // lgkmcnt(0) at the next barrier before any producer can overwrite.
    }
}

extern "C" void kernel_launch(void* const* d_in, const int* in_sizes, int n_in,
                              void* d_out, int out_size, void* d_ws, size_t ws_size,
                              hipStream_t stream) {
    const float* x        = (const float*)d_in[0];
    const float* dt       = (const float*)d_in[1];
    const float* log_freq = (const float*)d_in[2];
    const float* W_in     = (const float*)d_in[3];
    const float* W_out    = (const float*)d_in[4];
    const float* b_out    = (const float*)d_in[5];
    float* out = (float*)d_out;

    float* Ddt = (float*)d_ws;                        // 512 f32 = 2 KB

    int write_imag = (out_size >= (int)(OUT0 + 2u * HF_N)) ? 1 : 0;

    k_scan<<<1, T_DIM, 0, stream>>>(dt, Ddt);
    k_main<<<N_SEQ, 256, 0, stream>>>(x, W_in, W_out, b_out, log_freq, Ddt, out, write_imag);
}